// Round 2
// baseline (607.942 us; speedup 1.0000x reference)
//
#include <hip/hip_runtime.h>
#include <hip/hip_bf16.h>

#define B_ 4
#define T_ 2048
#define C_ 1024
#define H_ 16
#define D_ 64
#define M_ (B_*T_)   // 8192

typedef __bf16 bf16x8 __attribute__((ext_vector_type(8)));
typedef float  f32x4  __attribute__((ext_vector_type(4)));

static __device__ __forceinline__ f32x4 mfma16(bf16x8 a, bf16x8 b, f32x4 c){
  return __builtin_amdgcn_mfma_f32_16x16x32_bf16(a, b, c, 0, 0, 0);
}

typedef const __attribute__((address_space(1))) void gas_void;
typedef __attribute__((address_space(3))) void las_void;
static __device__ __forceinline__ void gload_lds16(const void* g, const void* l){
  __builtin_amdgcn_global_load_lds((gas_void*)(unsigned long long)g,
                                   (las_void*)(unsigned int)(unsigned long long)l,
                                   16, 0, 0);
}

static __device__ __forceinline__ unsigned short f2bf(float f){
  union { float f; unsigned int i; } v; v.f = f;
  return (unsigned short)((v.i + 0x7fffu + ((v.i >> 16) & 1u)) >> 16);
}

// ---------------- f32 -> bf16 convert (vectorized, 8 elems/thread) ----------------
__global__ __launch_bounds__(256)
void convert_k(const float* __restrict__ src, unsigned short* __restrict__ dst, int n8)
{
  int i = blockIdx.x * 256 + threadIdx.x;
  if (i >= n8) return;
  const float4* s = (const float4*)(src + (size_t)i*8);
  float4 a = s[0], b = s[1];
  unsigned short o[8] = { f2bf(a.x), f2bf(a.y), f2bf(a.z), f2bf(a.w),
                          f2bf(b.x), f2bf(b.y), f2bf(b.z), f2bf(b.w) };
  *(uint4*)(dst + (size_t)i*8) = *(const uint4*)o;
}

// ---------------- GEMM: C[m][n] = sum_k A[m][k]*W[n][k] + bias[n] ----------------
// MODE 0: out[b][h][t][d] bf16 (Q,K)  MODE 1: out[b][h][d][t] bf16 (Vt)  MODE 2: out[m][n] f32
template<int MODE>
__global__ __launch_bounds__(256)
void gemm_bias_k(const unsigned short* __restrict__ A,
                 const unsigned short* __restrict__ W,
                 const float* __restrict__ bias,
                 void* __restrict__ Cout_v)
{
  constexpr int TM = 128, BK = 32;
  __shared__ alignas(16) unsigned short As[2][TM*BK];
  __shared__ alignas(16) unsigned short Bs[2][TM*BK];
  const int tid = threadIdx.x;
  const int lane = tid & 63;
  const int wid  = tid >> 6;
  const int wm = wid >> 1, wn = wid & 1;          // 2x2 waves -> 64x64 each
  const int g = lane >> 4, r = lane & 15;
  const int m0 = blockIdx.y * TM, n0 = blockIdx.x * TM;

  f32x4 acc[4][4] = {};

  auto stage = [&](int buf, int kt){
    #pragma unroll
    for (int i = 0; i < 2; ++i){
      int c = tid + i*256;
      int row = c >> 2, col = (c & 3) << 3;
      gload_lds16(&A[(size_t)(m0+row)*C_ + kt*BK + col], &As[buf][c*8]);
    }
    #pragma unroll
    for (int i = 0; i < 2; ++i){
      int c = tid + i*256;
      int row = c >> 2, col = (c & 3) << 3;
      gload_lds16(&W[(size_t)(n0+row)*C_ + kt*BK + col], &Bs[buf][c*8]);
    }
  };

  stage(0, 0);
  const int nkt = C_/BK; // 32
  for (int kt = 0; kt < nkt; ++kt){
    int cur = kt & 1;
    if (kt + 1 < nkt) stage(cur^1, kt+1);
    __syncthreads();                 // drains vmcnt -> cur buffer ready
    bf16x8 af[4], bfv[4];
    #pragma unroll
    for (int mf = 0; mf < 4; ++mf)
      af[mf] = *(const bf16x8*)&As[cur][(wm*64 + mf*16 + r)*BK + g*8];
    #pragma unroll
    for (int nf = 0; nf < 4; ++nf)
      bfv[nf] = *(const bf16x8*)&Bs[cur][(wn*64 + nf*16 + r)*BK + g*8];
    #pragma unroll
    for (int mf = 0; mf < 4; ++mf)
      #pragma unroll
      for (int nf = 0; nf < 4; ++nf)
        acc[mf][nf] = mfma16(af[mf], bfv[nf], acc[mf][nf]);
    __syncthreads();                 // all waves done reading before overwrite
  }

  float bv[4];
  #pragma unroll
  for (int nf = 0; nf < 4; ++nf) bv[nf] = bias[n0 + wn*64 + nf*16 + r];

  #pragma unroll
  for (int mf = 0; mf < 4; ++mf){
    #pragma unroll
    for (int nf = 0; nf < 4; ++nf){
      int n = n0 + wn*64 + nf*16 + r;
      #pragma unroll
      for (int j = 0; j < 4; ++j){
        int m = m0 + wm*64 + mf*16 + g*4 + j;
        float val = acc[mf][nf][j] + bv[nf];
        if (MODE == 2){
          ((float*)Cout_v)[(size_t)m*C_ + n] = val;
        } else {
          int b = m >> 11, t = m & (T_-1), h = n >> 6, d = n & 63;
          size_t addr;
          if (MODE == 0) addr = ((((size_t)b*H_ + h)*T_ + t) << 6) + d;
          else           addr = (((size_t)b*H_ + h)*D_ + d)*T_ + t;
          ((unsigned short*)Cout_v)[addr] = f2bf(val);
        }
      }
    }
  }
}

// ---------------- Flash attention (causal), Q[B,H,T,D], K[B,H,T,D], Vt[B,H,D,T] ----
__global__ __launch_bounds__(256)
void attn_k(const unsigned short* __restrict__ Q,
            const unsigned short* __restrict__ K,
            const unsigned short* __restrict__ Vt,
            unsigned short* __restrict__ ctx)
{
  __shared__ alignas(16) unsigned short pbuf[4][16*64];  // per-wave P tile, XOR-swizzled
  const int tid = threadIdx.x;
  const int lane = tid & 63, w = tid >> 6;
  const int g = lane >> 4, r = lane & 15;
  const int qt = blockIdx.x, bh = blockIdx.y;
  const int q0 = qt * 64;
  const size_t base = (size_t)bh * T_ * D_;

  const int qrow = q0 + w*16 + r;
  bf16x8 qa0 = *(const bf16x8*)&Q[base + (size_t)qrow*D_ + g*8];
  bf16x8 qa1 = *(const bf16x8*)&Q[base + (size_t)qrow*D_ + 32 + g*8];

  float m_old[4], l_run[4];
  f32x4 oacc[4] = {};
  #pragma unroll
  for (int j = 0; j < 4; ++j){ m_old[j] = -1e30f; l_run[j] = 0.f; }

  const int myrow = q0 + w*16 + g*4;     // + j
  const int nt = qt + 1;
  for (int kv = 0; kv < nt; ++kv){
    const int kv0 = kv*64;
    f32x4 s[4];
    #pragma unroll
    for (int nf = 0; nf < 4; ++nf){
      bf16x8 kb0 = *(const bf16x8*)&K[base + (size_t)(kv0 + nf*16 + r)*D_ + g*8];
      bf16x8 kb1 = *(const bf16x8*)&K[base + (size_t)(kv0 + nf*16 + r)*D_ + 32 + g*8];
      f32x4 t = {};
      t = mfma16(qa0, kb0, t);
      t = mfma16(qa1, kb1, t);
      s[nf] = t;
    }
    float mx[4] = {-1e30f, -1e30f, -1e30f, -1e30f};
    #pragma unroll
    for (int nf = 0; nf < 4; ++nf){
      int col = kv0 + nf*16 + r;
      #pragma unroll
      for (int j = 0; j < 4; ++j){
        float v = s[nf][j] * 0.125f;
        v = (col > myrow + j) ? -1e30f : v;
        s[nf][j] = v;
        mx[j] = fmaxf(mx[j], v);
      }
    }
    #pragma unroll
    for (int off = 1; off < 16; off <<= 1){
      #pragma unroll
      for (int j = 0; j < 4; ++j) mx[j] = fmaxf(mx[j], __shfl_xor(mx[j], off, 64));
    }
    float mnew[4], alpha[4], rs[4];
    #pragma unroll
    for (int j = 0; j < 4; ++j){
      mnew[j]  = fmaxf(m_old[j], mx[j]);
      alpha[j] = __expf(m_old[j] - mnew[j]);
      rs[j] = 0.f;
    }
    #pragma unroll
    for (int nf = 0; nf < 4; ++nf){
      #pragma unroll
      for (int j = 0; j < 4; ++j){
        float p = __expf(s[nf][j] - mnew[j]);
        rs[j] += p;
        int prow = g*4 + j;
        int byteoff = (prow*128 + (nf*16 + r)*2) ^ ((prow & 7) << 4);
        *(unsigned short*)((char*)&pbuf[w][0] + byteoff) = f2bf(p);
      }
    }
    #pragma unroll
    for (int off = 1; off < 16; off <<= 1){
      #pragma unroll
      for (int j = 0; j < 4; ++j) rs[j] += __shfl_xor(rs[j], off, 64);
    }
    #pragma unroll
    for (int j = 0; j < 4; ++j){
      l_run[j] = l_run[j]*alpha[j] + rs[j];
      m_old[j] = mnew[j];
    }
    #pragma unroll
    for (int nf = 0; nf < 4; ++nf)
      #pragma unroll
      for (int j = 0; j < 4; ++j) oacc[nf][j] *= alpha[j];
    __syncthreads();
    bf16x8 pa0, pa1;
    {
      int b0 = (r*128 + g*16)      ^ ((r & 7) << 4);
      int b1 = (r*128 + 64 + g*16) ^ ((r & 7) << 4);
      pa0 = *(const bf16x8*)((char*)&pbuf[w][0] + b0);
      pa1 = *(const bf16x8*)((char*)&pbuf[w][0] + b1);
    }
    #pragma unroll
    for (int nf = 0; nf < 4; ++nf){
      bf16x8 vb0 = *(const bf16x8*)&Vt[base + (size_t)(nf*16 + r)*T_ + kv0 + g*8];
      bf16x8 vb1 = *(const bf16x8*)&Vt[base + (size_t)(nf*16 + r)*T_ + kv0 + 32 + g*8];
      oacc[nf] = mfma16(pa0, vb0, oacc[nf]);
      oacc[nf] = mfma16(pa1, vb1, oacc[nf]);
    }
    __syncthreads();
  }
  const int b = bh >> 4, h = bh & 15;
  #pragma unroll
  for (int nf = 0; nf < 4; ++nf){
    #pragma unroll
    for (int j = 0; j < 4; ++j){
      float val = oacc[nf][j] / l_run[j];
      int t = q0 + w*16 + g*4 + j;
      ctx[((size_t)b*T_ + t)*C_ + h*64 + nf*16 + r] = f2bf(val);
    }
  }
}

extern "C" void kernel_launch(void* const* d_in, const int* in_sizes, int n_in,
                              void* d_out, int out_size, void* d_ws, size_t ws_size,
                              hipStream_t stream)
{
  const float* x  = (const float*)d_in[0];
  const float* Wq = (const float*)d_in[1];
  const float* bq = (const float*)d_in[2];
  const float* Wk = (const float*)d_in[3];
  const float* bk = (const float*)d_in[4];
  const float* Wv = (const float*)d_in[5];
  const float* bv = (const float*)d_in[6];
  const float* Wo = (const float*)d_in[7];
  const float* bo = (const float*)d_in[8];
  float* out = (float*)d_out;

  const size_t NELT = (size_t)M_ * C_;   // 8.39M
  const size_t WELT = (size_t)C_ * C_;   // 1.05M
  unsigned short* xb  = (unsigned short*)d_ws;
  unsigned short* Wqb = xb  + NELT;
  unsigned short* Wkb = Wqb + WELT;
  unsigned short* Wvb = Wkb + WELT;
  unsigned short* Wob = Wvb + WELT;
  unsigned short* Qb  = Wob + WELT;
  unsigned short* Kb  = Qb  + NELT;
  unsigned short* Vtb = Kb  + NELT;
  unsigned short* ctx = Vtb + NELT;

  // f32 -> bf16 converts
  convert_k<<<(int)(NELT/8/256), 256, 0, stream>>>(x,  xb,  (int)(NELT/8));
  convert_k<<<(int)(WELT/8/256), 256, 0, stream>>>(Wq, Wqb, (int)(WELT/8));
  convert_k<<<(int)(WELT/8/256), 256, 0, stream>>>(Wk, Wkb, (int)(WELT/8));
  convert_k<<<(int)(WELT/8/256), 256, 0, stream>>>(Wv, Wvb, (int)(WELT/8));
  convert_k<<<(int)(WELT/8/256), 256, 0, stream>>>(Wo, Wob, (int)(WELT/8));

  dim3 gg(C_/128, M_/128);  // (8, 64)
  gemm_bias_k<0><<<gg, 256, 0, stream>>>(xb, Wqb, bq, Qb);
  gemm_bias_k<0><<<gg, 256, 0, stream>>>(xb, Wkb, bk, Kb);
  gemm_bias_k<1><<<gg, 256, 0, stream>>>(xb, Wvb, bv, Vtb);
  attn_k<<<dim3(T_/64, B_*H_), 256, 0, stream>>>(Qb, Kb, Vtb, ctx);
  gemm_bias_k<2><<<gg, 256, 0, stream>>>(ctx, Wob, bo, out);
}

// Round 3
// 375.393 us; speedup vs baseline: 1.6195x; 1.6195x over previous
//
#include <hip/hip_runtime.h>
#include <hip/hip_bf16.h>

#define B_ 4
#define T_ 2048
#define C_ 1024
#define H_ 16
#define D_ 64
#define M_ (B_*T_)   // 8192

typedef __bf16 bf16x8 __attribute__((ext_vector_type(8)));
typedef float  f32x4  __attribute__((ext_vector_type(4)));
typedef float  f32x16 __attribute__((ext_vector_type(16)));
typedef int    i32x2v __attribute__((ext_vector_type(2)));

static __device__ __forceinline__ f32x4 mfma16(bf16x8 a, bf16x8 b, f32x4 c){
  return __builtin_amdgcn_mfma_f32_16x16x32_bf16(a, b, c, 0, 0, 0);
}
static __device__ __forceinline__ f32x16 mfma32(bf16x8 a, bf16x8 b, f32x16 c){
  return __builtin_amdgcn_mfma_f32_32x32x16_bf16(a, b, c, 0, 0, 0);
}

typedef const __attribute__((address_space(1))) void gas_void;
typedef __attribute__((address_space(3))) void las_void;
static __device__ __forceinline__ void gload_lds16(const void* g, const void* l){
  __builtin_amdgcn_global_load_lds((gas_void*)(unsigned long long)g,
                                   (las_void*)(unsigned int)(unsigned long long)l,
                                   16, 0, 0);
}

static __device__ __forceinline__ unsigned short f2bf(float f){
  union { float f; unsigned int i; } v; v.f = f;
  return (unsigned short)((v.i + 0x7fffu + ((v.i >> 16) & 1u)) >> 16);
}
static __device__ __forceinline__ unsigned cvtpk(float lo, float hi){
  unsigned r; asm("v_cvt_pk_bf16_f32 %0, %1, %2" : "=v"(r) : "v"(lo), "v"(hi)); return r;
}
static __device__ __forceinline__ float ex2(float x){ return __builtin_amdgcn_exp2f(x); }

// ---------------- f32 -> bf16 convert (8 elems/thread) ----------------
__global__ __launch_bounds__(256)
void convert_k(const float* __restrict__ src, unsigned short* __restrict__ dst, int n8)
{
  int i = blockIdx.x * 256 + threadIdx.x;
  if (i >= n8) return;
  const float4* s = (const float4*)(src + (size_t)i*8);
  float4 a = s[0], b = s[1];
  unsigned short o[8] = { f2bf(a.x), f2bf(a.y), f2bf(a.z), f2bf(a.w),
                          f2bf(b.x), f2bf(b.y), f2bf(b.z), f2bf(b.w) };
  *(uint4*)(dst + (size_t)i*8) = *(const uint4*)o;
}

// ---------------- GEMM: C[m][n] = (sum_k A[m][k]*W[n][k] + bias[n]) * scale ----------
// MODE 0: out[b][h][t][d] bf16 (Q,K)  MODE 1: out[b][h][d][t] bf16 (Vt)  MODE 2: out[m][n] f32
template<int MODE>
__global__ __launch_bounds__(256)
void gemm_bias_k(const unsigned short* __restrict__ A,
                 const unsigned short* __restrict__ W,
                 const float* __restrict__ bias,
                 void* __restrict__ Cout_v, float scale)
{
  constexpr int TM = 128, BK = 32;
  __shared__ alignas(16) unsigned short As[2][TM*BK];
  __shared__ alignas(16) unsigned short Bs[2][TM*BK];
  const int tid = threadIdx.x;
  const int lane = tid & 63;
  const int wid  = tid >> 6;
  const int wm = wid >> 1, wn = wid & 1;          // 2x2 waves -> 64x64 each
  const int g = lane >> 4, r = lane & 15;
  const int m0 = blockIdx.y * TM, n0 = blockIdx.x * TM;

  f32x4 acc[4][4] = {};

  auto stage = [&](int buf, int kt){
    #pragma unroll
    for (int i = 0; i < 2; ++i){
      int c = tid + i*256;
      int row = c >> 2, col = (c & 3) << 3;
      gload_lds16(&A[(size_t)(m0+row)*C_ + kt*BK + col], &As[buf][c*8]);
    }
    #pragma unroll
    for (int i = 0; i < 2; ++i){
      int c = tid + i*256;
      int row = c >> 2, col = (c & 3) << 3;
      gload_lds16(&W[(size_t)(n0+row)*C_ + kt*BK + col], &Bs[buf][c*8]);
    }
  };

  stage(0, 0);
  const int nkt = C_/BK; // 32
  for (int kt = 0; kt < nkt; ++kt){
    int cur = kt & 1;
    if (kt + 1 < nkt) stage(cur^1, kt+1);
    __syncthreads();
    bf16x8 af[4], bfv[4];
    #pragma unroll
    for (int mf = 0; mf < 4; ++mf)
      af[mf] = *(const bf16x8*)&As[cur][(wm*64 + mf*16 + r)*BK + g*8];
    #pragma unroll
    for (int nf = 0; nf < 4; ++nf)
      bfv[nf] = *(const bf16x8*)&Bs[cur][(wn*64 + nf*16 + r)*BK + g*8];
    #pragma unroll
    for (int mf = 0; mf < 4; ++mf)
      #pragma unroll
      for (int nf = 0; nf < 4; ++nf)
        acc[mf][nf] = mfma16(af[mf], bfv[nf], acc[mf][nf]);
    __syncthreads();
  }

  float bv[4];
  #pragma unroll
  for (int nf = 0; nf < 4; ++nf) bv[nf] = bias[n0 + wn*64 + nf*16 + r];

  #pragma unroll
  for (int mf = 0; mf < 4; ++mf){
    #pragma unroll
    for (int nf = 0; nf < 4; ++nf){
      int n = n0 + wn*64 + nf*16 + r;
      #pragma unroll
      for (int j = 0; j < 4; ++j){
        int m = m0 + wm*64 + mf*16 + g*4 + j;
        float val = (acc[mf][nf][j] + bv[nf]) * scale;
        if (MODE == 2){
          ((float*)Cout_v)[(size_t)m*C_ + n] = val;
        } else {
          int b = m >> 11, t = m & (T_-1), h = n >> 6, d = n & 63;
          size_t addr;
          if (MODE == 0) addr = ((((size_t)b*H_ + h)*T_ + t) << 6) + d;
          else           addr = (((size_t)b*H_ + h)*D_ + d)*T_ + t;
          ((unsigned short*)Cout_v)[addr] = f2bf(val);
        }
      }
    }
  }
}

// ---------------- Flash attention v2: swapped QK^T, 32x32x16, no barriers ----------
// Q[B,H,T,D] (pre-scaled by 0.125*log2e), K[B,H,T,D], Vt[B,H,D,T] -> ctx[B,T,C] bf16
__global__ __launch_bounds__(256)
void attn_k(const unsigned short* __restrict__ Q,
            const unsigned short* __restrict__ K,
            const unsigned short* __restrict__ Vt,
            unsigned short* __restrict__ ctx)
{
  __shared__ alignas(16) unsigned short obuf[4][32*64];  // per-warp transpose buffer
  const int tid  = threadIdx.x;
  const int lane = tid & 63, w = tid >> 6;
  const int h    = lane >> 5;      // lane half
  const int ql   = lane & 31;      // q column within warp tile
  const int bh   = blockIdx.y;
  const int qblk = (T_/128 - 1) - blockIdx.x;   // heavy blocks first
  const int qlo  = qblk * 128 + w * 32;
  const size_t base = (size_t)bh * T_ * D_;

  // Q fragments (B-operand): lane holds Q[qlo+ql][kc*16 + h*8 .. +7]
  bf16x8 qf[4];
  #pragma unroll
  for (int kc = 0; kc < 4; ++kc)
    qf[kc] = *(const bf16x8*)&Q[base + (size_t)(qlo + ql)*D_ + kc*16 + h*8];

  f32x16 oacc[2] = {};
  float m_run = -1e30f, l_run = 0.f;

  auto tile = [&](int kv0, bool partial){
    // ---- QK^T (swapped): st[t] = S^T tile, rows kv, cols q ----
    f32x16 st[2];
    #pragma unroll
    for (int t = 0; t < 2; ++t){
      f32x16 s = {};
      #pragma unroll
      for (int kc = 0; kc < 4; ++kc){
        bf16x8 kf = *(const bf16x8*)&K[base + (size_t)(kv0 + t*32 + ql)*D_ + kc*16 + h*8];
        s = mfma32(kf, qf[kc], s);
      }
      st[t] = s;
    }
    // ---- V fragments (A-operand of PV), independent: issue early ----
    bf16x8 vf[2][4];
    #pragma unroll
    for (int dt = 0; dt < 2; ++dt)
      #pragma unroll
      for (int c = 0; c < 4; ++c)
        vf[dt][c] = *(const bf16x8*)&Vt[base + (size_t)(dt*32 + ql)*T_ + kv0 + c*16 + h*8];

    // ---- mask + row max (per lane: 32 values of one q-row) ----
    float p[32];
    #pragma unroll
    for (int t = 0; t < 2; ++t)
      #pragma unroll
      for (int rg = 0; rg < 16; ++rg){
        float v = st[t][rg];
        if (partial){
          int kvi = kv0 + t*32 + (rg&3) + 8*(rg>>2) + 4*h;
          v = (kvi > qlo + ql) ? -1e30f : v;
        }
        p[t*16+rg] = v;
      }
    float mx = p[0];
    #pragma unroll
    for (int i = 1; i < 32; ++i) mx = fmaxf(mx, p[i]);
    mx = fmaxf(mx, __shfl_xor(mx, 32, 64));
    float mnew  = fmaxf(m_run, mx);
    float alpha = ex2(m_run - mnew);
    // ---- exp + row sum ----
    float rs = 0.f;
    #pragma unroll
    for (int i = 0; i < 32; ++i){ p[i] = ex2(p[i] - mnew); rs += p[i]; }
    rs += __shfl_xor(rs, 32, 64);
    l_run = l_run * alpha + rs;
    m_run = mnew;
    // ---- rescale O ----
    oacc[0] = oacc[0] * alpha;
    oacc[1] = oacc[1] * alpha;
    // ---- P -> bf16 B-frags via cvt_pk + permlane32_swap ----
    bf16x8 pf[4];
    #pragma unroll
    for (int t = 0; t < 2; ++t)
      #pragma unroll
      for (int cl = 0; cl < 2; ++cl){
        int b0 = t*16 + cl*8;
        unsigned pkA = cvtpk(p[b0+0], p[b0+1]);
        unsigned pkB = cvtpk(p[b0+4], p[b0+5]);
        unsigned pkC = cvtpk(p[b0+2], p[b0+3]);
        unsigned pkD = cvtpk(p[b0+6], p[b0+7]);
        i32x2v r02 = __builtin_amdgcn_permlane32_swap((int)pkA, (int)pkB, false, false);
        i32x2v r13 = __builtin_amdgcn_permlane32_swap((int)pkC, (int)pkD, false, false);
        union { int d[4]; bf16x8 v; } u;
        u.d[0] = r02[0]; u.d[1] = r13[0]; u.d[2] = r02[1]; u.d[3] = r13[1];
        pf[t*2+cl] = u.v;
      }
    // ---- PV: O^T accumulate ----
    #pragma unroll
    for (int dt = 0; dt < 2; ++dt)
      #pragma unroll
      for (int c = 0; c < 4; ++c)
        oacc[dt] = mfma32(vf[dt][c], pf[c], oacc[dt]);
  };

  const int nfull = qlo >> 6;
  for (int kv = 0; kv < nfull; ++kv) tile(kv*64, false);
  tile(nfull*64, true);

  // ---- epilogue: O^T -> LDS (swizzled) -> coalesced global ----
  float inv = __builtin_amdgcn_rcpf(l_run);
  unsigned short* ob = &obuf[w][0];
  #pragma unroll
  for (int dt = 0; dt < 2; ++dt)
    #pragma unroll
    for (int rg = 0; rg < 16; rg += 2){
      int d = dt*32 + (rg&3) + 8*(rg>>2) + 4*h;
      unsigned pk = cvtpk(oacc[dt][rg]*inv, oacc[dt][rg+1]*inv);
      int off = (ql*128 + d*2) ^ ((ql&7)<<4);
      *(unsigned*)((char*)ob + off) = pk;
    }
  __builtin_amdgcn_s_waitcnt(0);  // lgkmcnt(0): LDS writes visible (same wave)
  const int bb = bh >> 4, hh = bh & 15;
  const size_t orow = ((size_t)bb*T_ + qlo + ql)*C_ + hh*64 + h*32;
  #pragma unroll
  for (int x = 0; x < 4; ++x){
    int off = (ql*128 + h*64 + x*16) ^ ((ql&7)<<4);
    bf16x8 v = *(const bf16x8*)((const char*)ob + off);
    *(bf16x8*)&ctx[orow + x*8] = v;
  }
}

extern "C" void kernel_launch(void* const* d_in, const int* in_sizes, int n_in,
                              void* d_out, int out_size, void* d_ws, size_t ws_size,
                              hipStream_t stream)
{
  const float* x  = (const float*)d_in[0];
  const float* Wq = (const float*)d_in[1];
  const float* bq = (const float*)d_in[2];
  const float* Wk = (const float*)d_in[3];
  const float* bk = (const float*)d_in[4];
  const float* Wv = (const float*)d_in[5];
  const float* bv = (const float*)d_in[6];
  const float* Wo = (const float*)d_in[7];
  const float* bo = (const float*)d_in[8];
  float* out = (float*)d_out;

  const size_t NELT = (size_t)M_ * C_;   // 8.39M
  const size_t WELT = (size_t)C_ * C_;   // 1.05M
  unsigned short* xb  = (unsigned short*)d_ws;
  unsigned short* Wqb = xb  + NELT;
  unsigned short* Wkb = Wqb + WELT;
  unsigned short* Wvb = Wkb + WELT;
  unsigned short* Wob = Wvb + WELT;
  unsigned short* Qb  = Wob + WELT;
  unsigned short* Kb  = Qb  + NELT;
  unsigned short* Vtb = Kb  + NELT;
  unsigned short* ctx = Vtb + NELT;

  convert_k<<<(int)(NELT/8/256), 256, 0, stream>>>(x,  xb,  (int)(NELT/8));
  convert_k<<<(int)(WELT/8/256), 256, 0, stream>>>(Wq, Wqb, (int)(WELT/8));
  convert_k<<<(int)(WELT/8/256), 256, 0, stream>>>(Wk, Wkb, (int)(WELT/8));
  convert_k<<<(int)(WELT/8/256), 256, 0, stream>>>(Wv, Wvb, (int)(WELT/8));
  convert_k<<<(int)(WELT/8/256), 256, 0, stream>>>(Wo, Wob, (int)(WELT/8));

  const float SCALE_Q = 0.125f * 1.4426950408889634f;  // (1/sqrt(64)) * log2(e)
  dim3 gg(C_/128, M_/128);  // (8, 64)
  gemm_bias_k<0><<<gg, 256, 0, stream>>>(xb, Wqb, bq, Qb, SCALE_Q);
  gemm_bias_k<0><<<gg, 256, 0, stream>>>(xb, Wkb, bk, Kb, 1.0f);
  gemm_bias_k<1><<<gg, 256, 0, stream>>>(xb, Wvb, bv, Vtb, 1.0f);
  attn_k<<<dim3(T_/128, B_*H_), 256, 0, stream>>>(Qb, Kb, Vtb, ctx);
  gemm_bias_k<2><<<gg, 256, 0, stream>>>(ctx, Wob, bo, out, 1.0f);
}

// Round 4
// 274.142 us; speedup vs baseline: 2.2176x; 1.3693x over previous
//
#include <hip/hip_runtime.h>
#include <hip/hip_bf16.h>

#define B_ 4
#define T_ 2048
#define C_ 1024
#define H_ 16
#define D_ 64
#define M_ (B_*T_)   // 8192

typedef __bf16 bf16x8 __attribute__((ext_vector_type(8)));
typedef float  f32x4  __attribute__((ext_vector_type(4)));
typedef float  f32x16 __attribute__((ext_vector_type(16)));
typedef int    i32x2v __attribute__((ext_vector_type(2)));

static __device__ __forceinline__ f32x4 mfma16(bf16x8 a, bf16x8 b, f32x4 c){
  return __builtin_amdgcn_mfma_f32_16x16x32_bf16(a, b, c, 0, 0, 0);
}
static __device__ __forceinline__ f32x16 mfma32(bf16x8 a, bf16x8 b, f32x16 c){
  return __builtin_amdgcn_mfma_f32_32x32x16_bf16(a, b, c, 0, 0, 0);
}

typedef const __attribute__((address_space(1))) void gas_void;
typedef __attribute__((address_space(3))) void las_void;
static __device__ __forceinline__ void gload_lds16(const void* g, const void* l){
  __builtin_amdgcn_global_load_lds((gas_void*)(unsigned long long)g,
                                   (las_void*)(unsigned int)(unsigned long long)l,
                                   16, 0, 0);
}

static __device__ __forceinline__ unsigned short f2bf(float f){
  union { float f; unsigned int i; } v; v.f = f;
  return (unsigned short)((v.i + 0x7fffu + ((v.i >> 16) & 1u)) >> 16);
}
static __device__ __forceinline__ unsigned cvtpk(float lo, float hi){
  unsigned r; asm("v_cvt_pk_bf16_f32 %0, %1, %2" : "=v"(r) : "v"(lo), "v"(hi)); return r;
}
static __device__ __forceinline__ float ex2(float x){ return __builtin_amdgcn_exp2f(x); }

// ---------------- f32 -> bf16 convert (8 elems/thread) ----------------
__global__ __launch_bounds__(256)
void convert_k(const float* __restrict__ src, unsigned short* __restrict__ dst, int n8)
{
  int i = blockIdx.x * 256 + threadIdx.x;
  if (i >= n8) return;
  const float4* s = (const float4*)(src + (size_t)i*8);
  float4 a = s[0], b = s[1];
  unsigned short o[8] = { f2bf(a.x), f2bf(a.y), f2bf(a.z), f2bf(a.w),
                          f2bf(b.x), f2bf(b.y), f2bf(b.z), f2bf(b.w) };
  *(uint4*)(dst + (size_t)i*8) = *(const uint4*)o;
}

// ---------------- GEMM: C[m][n] = (sum_k A[m][k]*W[n][k] + bias[n]) * scale ----------
// MODE 0: out[b][h][t][d] bf16 (Q,K)  MODE 1: out[b][h][d][t] bf16 (Vt)  MODE 2: out[m][n] f32
template<int MODE>
__global__ __launch_bounds__(256)
void gemm_bias_k(const unsigned short* __restrict__ A,
                 const unsigned short* __restrict__ W,
                 const float* __restrict__ bias,
                 void* __restrict__ Cout_v, float scale)
{
  constexpr int TM = 128, BK = 32;
  __shared__ alignas(16) unsigned short As[2][TM*BK];
  __shared__ alignas(16) unsigned short Bs[2][TM*BK];
  const int tid = threadIdx.x;
  const int lane = tid & 63;
  const int wid  = tid >> 6;
  const int wm = wid >> 1, wn = wid & 1;          // 2x2 waves -> 64x64 each
  const int g = lane >> 4, r = lane & 15;
  const int m0 = blockIdx.y * TM, n0 = blockIdx.x * TM;

  f32x4 acc[4][4] = {};

  auto stage = [&](int buf, int kt){
    #pragma unroll
    for (int i = 0; i < 2; ++i){
      int c = tid + i*256;
      int row = c >> 2, col = (c & 3) << 3;
      gload_lds16(&A[(size_t)(m0+row)*C_ + kt*BK + col], &As[buf][c*8]);
    }
    #pragma unroll
    for (int i = 0; i < 2; ++i){
      int c = tid + i*256;
      int row = c >> 2, col = (c & 3) << 3;
      gload_lds16(&W[(size_t)(n0+row)*C_ + kt*BK + col], &Bs[buf][c*8]);
    }
  };

  stage(0, 0);
  const int nkt = C_/BK; // 32
  for (int kt = 0; kt < nkt; ++kt){
    int cur = kt & 1;
    if (kt + 1 < nkt) stage(cur^1, kt+1);
    __syncthreads();
    bf16x8 af[4], bfv[4];
    #pragma unroll
    for (int mf = 0; mf < 4; ++mf)
      af[mf] = *(const bf16x8*)&As[cur][(wm*64 + mf*16 + r)*BK + g*8];
    #pragma unroll
    for (int nf = 0; nf < 4; ++nf)
      bfv[nf] = *(const bf16x8*)&Bs[cur][(wn*64 + nf*16 + r)*BK + g*8];
    #pragma unroll
    for (int mf = 0; mf < 4; ++mf)
      #pragma unroll
      for (int nf = 0; nf < 4; ++nf)
        acc[mf][nf] = mfma16(af[mf], bfv[nf], acc[mf][nf]);
    __syncthreads();
  }

  float bv[4];
  #pragma unroll
  for (int nf = 0; nf < 4; ++nf) bv[nf] = bias[n0 + wn*64 + nf*16 + r];

  #pragma unroll
  for (int mf = 0; mf < 4; ++mf){
    #pragma unroll
    for (int nf = 0; nf < 4; ++nf){
      int n = n0 + wn*64 + nf*16 + r;
      #pragma unroll
      for (int j = 0; j < 4; ++j){
        int m = m0 + wm*64 + mf*16 + g*4 + j;
        float val = (acc[mf][nf][j] + bv[nf]) * scale;
        if (MODE == 2){
          ((float*)Cout_v)[(size_t)m*C_ + n] = val;
        } else {
          int b = m >> 11, t = m & (T_-1), h = n >> 6, d = n & 63;
          size_t addr;
          if (MODE == 0) addr = ((((size_t)b*H_ + h)*T_ + t) << 6) + d;
          else           addr = (((size_t)b*H_ + h)*D_ + d)*T_ + t;
          ((unsigned short*)Cout_v)[addr] = f2bf(val);
        }
      }
    }
  }
}

// ---------------- Flash attention v3: causal-paired, K-prefetch, no barriers ----------
// Q[B,H,T,D] (pre-scaled by 0.125*log2e), K[B,H,T,D], Vt[B,H,D,T] -> ctx[B,T,C] bf16
// grid: 512 blocks, wgid = pair*64 + bh  (keeps one bh's KV on one XCD's L2)
__global__ __launch_bounds__(256, 2)
void attn_k(const unsigned short* __restrict__ Q,
            const unsigned short* __restrict__ K,
            const unsigned short* __restrict__ Vt,
            unsigned short* __restrict__ ctx)
{
  __shared__ alignas(16) unsigned short obuf[4][32*64];  // per-warp transpose buffer
  const int tid  = threadIdx.x;
  const int lane = tid & 63, w = tid >> 6;
  const int h    = lane >> 5;      // lane half
  const int ql   = lane & 31;      // q column within warp tile
  const int wgid = blockIdx.x;
  const int pair = wgid >> 6;      // 0..7
  const int bh   = wgid & 63;
  const size_t base = (size_t)bh * T_ * D_;
  const int bb = bh >> 4, hh = bh & 15;

  #pragma unroll 1
  for (int hf = 0; hf < 2; ++hf){
    const int qblk = hf ? (15 - pair) : pair;
    const int qlo  = qblk * 128 + w * 32;

    bf16x8 qf[4];
    #pragma unroll
    for (int kc = 0; kc < 4; ++kc)
      qf[kc] = *(const bf16x8*)&Q[base + (size_t)(qlo + ql)*D_ + kc*16 + h*8];

    f32x16 oacc[2] = {};
    float m_run = -1e30f, l_run = 0.f;
    const int nfull = qlo >> 6;

    bf16x8 kf[2][4], kfn[2][4];
    #pragma unroll
    for (int t = 0; t < 2; ++t)
      #pragma unroll
      for (int kc = 0; kc < 4; ++kc)
        kf[t][kc] = *(const bf16x8*)&K[base + (size_t)(t*32 + ql)*D_ + kc*16 + h*8];

    for (int kv = 0; kv <= nfull; ++kv){
      const int kv0 = kv * 64;
      const bool partial = (kv == nfull);
      // ---- QK^T (swapped): S^T tile ----
      f32x16 st[2];
      #pragma unroll
      for (int t = 0; t < 2; ++t){
        f32x16 s = {};
        #pragma unroll
        for (int kc = 0; kc < 4; ++kc)
          s = mfma32(kf[t][kc], qf[kc], s);
        st[t] = s;
      }
      // ---- prefetch next K tile (hidden under softmax VALU chain) ----
      if (kv < nfull){
        #pragma unroll
        for (int t = 0; t < 2; ++t)
          #pragma unroll
          for (int kc = 0; kc < 4; ++kc)
            kfn[t][kc] = *(const bf16x8*)&K[base + (size_t)(kv0 + 64 + t*32 + ql)*D_ + kc*16 + h*8];
      }
      // ---- V fragments (A-operand of PV) ----
      bf16x8 vf[2][4];
      #pragma unroll
      for (int dt = 0; dt < 2; ++dt)
        #pragma unroll
        for (int c = 0; c < 4; ++c)
          vf[dt][c] = *(const bf16x8*)&Vt[base + (size_t)(dt*32 + ql)*T_ + kv0 + c*16 + h*8];

      // ---- mask + row max ----
      float p[32];
      #pragma unroll
      for (int t = 0; t < 2; ++t)
        #pragma unroll
        for (int rg = 0; rg < 16; ++rg){
          float v = st[t][rg];
          if (partial){
            int kvi = kv0 + t*32 + (rg&3) + 8*(rg>>2) + 4*h;
            v = (kvi > qlo + ql) ? -1e30f : v;
          }
          p[t*16+rg] = v;
        }
      float mx = p[0];
      #pragma unroll
      for (int i = 1; i < 32; ++i) mx = fmaxf(mx, p[i]);
      mx = fmaxf(mx, __shfl_xor(mx, 32, 64));
      float mnew  = fmaxf(m_run, mx);
      float alpha = ex2(m_run - mnew);
      float rs = 0.f;
      #pragma unroll
      for (int i = 0; i < 32; ++i){ p[i] = ex2(p[i] - mnew); rs += p[i]; }
      rs += __shfl_xor(rs, 32, 64);
      l_run = l_run * alpha + rs;
      m_run = mnew;
      oacc[0] = oacc[0] * alpha;
      oacc[1] = oacc[1] * alpha;
      // ---- P -> bf16 B-frags via cvt_pk + permlane32_swap ----
      bf16x8 pf[4];
      #pragma unroll
      for (int t = 0; t < 2; ++t)
        #pragma unroll
        for (int cl = 0; cl < 2; ++cl){
          int b0 = t*16 + cl*8;
          unsigned pkA = cvtpk(p[b0+0], p[b0+1]);
          unsigned pkB = cvtpk(p[b0+4], p[b0+5]);
          unsigned pkC = cvtpk(p[b0+2], p[b0+3]);
          unsigned pkD = cvtpk(p[b0+6], p[b0+7]);
          i32x2v r02 = __builtin_amdgcn_permlane32_swap((int)pkA, (int)pkB, false, false);
          i32x2v r13 = __builtin_amdgcn_permlane32_swap((int)pkC, (int)pkD, false, false);
          union { int d[4]; bf16x8 v; } u;
          u.d[0] = r02[0]; u.d[1] = r13[0]; u.d[2] = r02[1]; u.d[3] = r13[1];
          pf[t*2+cl] = u.v;
        }
      // ---- rotate K prefetch buffer ----
      if (kv < nfull){
        #pragma unroll
        for (int t = 0; t < 2; ++t)
          #pragma unroll
          for (int kc = 0; kc < 4; ++kc)
            kf[t][kc] = kfn[t][kc];
      }
      // ---- PV: O^T accumulate ----
      #pragma unroll
      for (int dt = 0; dt < 2; ++dt)
        #pragma unroll
        for (int c = 0; c < 4; ++c)
          oacc[dt] = mfma32(vf[dt][c], pf[c], oacc[dt]);
    }

    // ---- epilogue: O^T -> LDS (swizzled) -> coalesced global ----
    float inv = __builtin_amdgcn_rcpf(l_run);
    unsigned short* ob = &obuf[w][0];
    #pragma unroll
    for (int dt = 0; dt < 2; ++dt)
      #pragma unroll
      for (int rg = 0; rg < 16; rg += 2){
        int d = dt*32 + (rg&3) + 8*(rg>>2) + 4*h;
        unsigned pk = cvtpk(oacc[dt][rg]*inv, oacc[dt][rg+1]*inv);
        int off = (ql*128 + d*2) ^ ((ql&7)<<4);
        *(unsigned*)((char*)ob + off) = pk;
      }
    __builtin_amdgcn_s_waitcnt(0);  // LDS writes visible (same wave)
    const size_t orow = ((size_t)bb*T_ + qlo + ql)*C_ + hh*64 + h*32;
    #pragma unroll
    for (int x = 0; x < 4; ++x){
      int off = (ql*128 + h*64 + x*16) ^ ((ql&7)<<4);
      bf16x8 v = *(const bf16x8*)((const char*)ob + off);
      *(bf16x8*)&ctx[orow + x*8] = v;
    }
  }
}

extern "C" void kernel_launch(void* const* d_in, const int* in_sizes, int n_in,
                              void* d_out, int out_size, void* d_ws, size_t ws_size,
                              hipStream_t stream)
{
  const float* x  = (const float*)d_in[0];
  const float* Wq = (const float*)d_in[1];
  const float* bq = (const float*)d_in[2];
  const float* Wk = (const float*)d_in[3];
  const float* bk = (const float*)d_in[4];
  const float* Wv = (const float*)d_in[5];
  const float* bv = (const float*)d_in[6];
  const float* Wo = (const float*)d_in[7];
  const float* bo = (const float*)d_in[8];
  float* out = (float*)d_out;

  const size_t NELT = (size_t)M_ * C_;   // 8.39M
  const size_t WELT = (size_t)C_ * C_;   // 1.05M
  unsigned short* xb  = (unsigned short*)d_ws;
  unsigned short* Wqb = xb  + NELT;
  unsigned short* Wkb = Wqb + WELT;
  unsigned short* Wvb = Wkb + WELT;
  unsigned short* Wob = Wvb + WELT;
  unsigned short* Qb  = Wob + WELT;
  unsigned short* Kb  = Qb  + NELT;
  unsigned short* Vtb = Kb  + NELT;
  unsigned short* ctx = Vtb + NELT;

  convert_k<<<(int)(NELT/8/256), 256, 0, stream>>>(x,  xb,  (int)(NELT/8));
  convert_k<<<(int)(WELT/8/256), 256, 0, stream>>>(Wq, Wqb, (int)(WELT/8));
  convert_k<<<(int)(WELT/8/256), 256, 0, stream>>>(Wk, Wkb, (int)(WELT/8));
  convert_k<<<(int)(WELT/8/256), 256, 0, stream>>>(Wv, Wvb, (int)(WELT/8));
  convert_k<<<(int)(WELT/8/256), 256, 0, stream>>>(Wo, Wob, (int)(WELT/8));

  const float SCALE_Q = 0.125f * 1.4426950408889634f;  // (1/sqrt(64)) * log2(e)
  dim3 gg(C_/128, M_/128);  // (8, 64)
  gemm_bias_k<0><<<gg, 256, 0, stream>>>(xb, Wqb, bq, Qb, SCALE_Q);
  gemm_bias_k<0><<<gg, 256, 0, stream>>>(xb, Wkb, bk, Kb, 1.0f);
  gemm_bias_k<1><<<gg, 256, 0, stream>>>(xb, Wvb, bv, Vtb, 1.0f);
  attn_k<<<dim3(8*64), 256, 0, stream>>>(Qb, Kb, Vtb, ctx);
  gemm_bias_k<2><<<gg, 256, 0, stream>>>(ctx, Wob, bo, out, 1.0f);
}

// Round 5
// 250.392 us; speedup vs baseline: 2.4280x; 1.0948x over previous
//
#include <hip/hip_runtime.h>
#include <hip/hip_bf16.h>

#define B_ 4
#define T_ 2048
#define C_ 1024
#define H_ 16
#define D_ 64
#define M_ (B_*T_)   // 8192

typedef __bf16 bf16x8 __attribute__((ext_vector_type(8)));
typedef float  f32x4  __attribute__((ext_vector_type(4)));
typedef float  f32x16 __attribute__((ext_vector_type(16)));
typedef int    i32x2v __attribute__((ext_vector_type(2)));

static __device__ __forceinline__ f32x4 mfma16(bf16x8 a, bf16x8 b, f32x4 c){
  return __builtin_amdgcn_mfma_f32_16x16x32_bf16(a, b, c, 0, 0, 0);
}
static __device__ __forceinline__ f32x16 mfma32(bf16x8 a, bf16x8 b, f32x16 c){
  return __builtin_amdgcn_mfma_f32_32x32x16_bf16(a, b, c, 0, 0, 0);
}

typedef const __attribute__((address_space(1))) void gas_void;
typedef __attribute__((address_space(3))) void las_void;
static __device__ __forceinline__ void gload_lds16(const void* g, const void* l){
  __builtin_amdgcn_global_load_lds((gas_void*)(unsigned long long)g,
                                   (las_void*)(unsigned int)(unsigned long long)l,
                                   16, 0, 0);
}

static __device__ __forceinline__ unsigned short f2bf(float f){
  union { float f; unsigned int i; } v; v.f = f;
  return (unsigned short)((v.i + 0x7fffu + ((v.i >> 16) & 1u)) >> 16);
}
static __device__ __forceinline__ unsigned cvtpk(float lo, float hi){
  unsigned r; asm("v_cvt_pk_bf16_f32 %0, %1, %2" : "=v"(r) : "v"(lo), "v"(hi)); return r;
}
static __device__ __forceinline__ float ex2(float x){ return __builtin_amdgcn_exp2f(x); }

#define SCALE_Q (0.125f * 1.4426950408889634f)

// ---------------- fused f32 -> bf16 convert: x + Wq/Wk/Wv/Wo ----------------
__global__ __launch_bounds__(256)
void convert_all_k(const float* __restrict__ x,
                   const float* __restrict__ wq, const float* __restrict__ wk,
                   const float* __restrict__ wv, const float* __restrict__ wo,
                   unsigned short* __restrict__ dst)
{
  const int NX = (int)((size_t)M_*C_/8);    // 1048576
  const int NW = (int)((size_t)C_*C_/8);    // 131072
  int i = blockIdx.x * 256 + threadIdx.x;
  const float* src; unsigned short* dp; int o;
  if (i < NX){ src = x; dp = dst; o = i; }
  else {
    int j = i - NX; int rgn = j / NW; o = j - rgn*NW;
    src = rgn==0?wq : rgn==1?wk : rgn==2?wv : wo;
    dp  = dst + (size_t)M_*C_ + (size_t)rgn*C_*C_;
  }
  const float4* s = (const float4*)(src + (size_t)o*8);
  float4 a = s[0], b = s[1];
  unsigned short ov[8] = { f2bf(a.x), f2bf(a.y), f2bf(a.z), f2bf(a.w),
                           f2bf(b.x), f2bf(b.y), f2bf(b.z), f2bf(b.w) };
  *(uint4*)(dp + (size_t)o*8) = *(const uint4*)ov;
}

// ---------------- GEMM ----------------
// MODE 0: fused QKV — A[8192][1024] x W[3072][1024]^T; routes by n-range:
//   n<1024 -> Q [b][h][t][d] bf16, scaled; n<2048 -> K same; else Vt [b][h][d][t]
// MODE 2: out-proj — f32 out [m][n]
template<int MODE>
__global__ __launch_bounds__(256)
void gemm_bias_k(const unsigned short* __restrict__ A,
                 const unsigned short* __restrict__ W,
                 const float* __restrict__ b0p, const float* __restrict__ b1p,
                 const float* __restrict__ b2p,
                 void* __restrict__ Cout_v)
{
  constexpr int TM = 128, BK = 32;
  __shared__ alignas(16) unsigned short As[2][TM*BK];
  __shared__ alignas(16) unsigned short Bs[2][TM*BK];
  const int tid = threadIdx.x;
  const int lane = tid & 63;
  const int wid  = tid >> 6;
  const int wm = wid >> 1, wn = wid & 1;
  const int g = lane >> 4, r = lane & 15;
  const int m0 = blockIdx.y * TM, n0 = blockIdx.x * TM;

  f32x4 acc[4][4] = {};

  auto stage = [&](int buf, int kt){
    #pragma unroll
    for (int i = 0; i < 2; ++i){
      int c = tid + i*256;
      int row = c >> 2, col = (c & 3) << 3;
      gload_lds16(&A[(size_t)(m0+row)*C_ + kt*BK + col], &As[buf][c*8]);
    }
    #pragma unroll
    for (int i = 0; i < 2; ++i){
      int c = tid + i*256;
      int row = c >> 2, col = (c & 3) << 3;
      gload_lds16(&W[(size_t)(n0+row)*C_ + kt*BK + col], &Bs[buf][c*8]);
    }
  };

  stage(0, 0);
  const int nkt = C_/BK;
  for (int kt = 0; kt < nkt; ++kt){
    int cur = kt & 1;
    if (kt + 1 < nkt) stage(cur^1, kt+1);
    __syncthreads();
    bf16x8 af[4], bfv[4];
    #pragma unroll
    for (int mf = 0; mf < 4; ++mf)
      af[mf] = *(const bf16x8*)&As[cur][(wm*64 + mf*16 + r)*BK + g*8];
    #pragma unroll
    for (int nf = 0; nf < 4; ++nf)
      bfv[nf] = *(const bf16x8*)&Bs[cur][(wn*64 + nf*16 + r)*BK + g*8];
    #pragma unroll
    for (int mf = 0; mf < 4; ++mf)
      #pragma unroll
      for (int nf = 0; nf < 4; ++nf)
        acc[mf][nf] = mfma16(af[mf], bfv[nf], acc[mf][nf]);
    __syncthreads();
  }

  const int which = (MODE == 0) ? (n0 >> 10) : 0;
  const float* bp = (MODE == 0) ? (which==0 ? b0p : (which==1 ? b1p : b2p)) : b0p;
  const float scale = (MODE == 0 && which == 0) ? SCALE_Q : 1.0f;

  float bv[4];
  #pragma unroll
  for (int nf = 0; nf < 4; ++nf) bv[nf] = bp[(n0 + wn*64 + nf*16 + r) & (MODE==0 ? 1023 : (C_-1))];

  #pragma unroll
  for (int mf = 0; mf < 4; ++mf){
    #pragma unroll
    for (int nf = 0; nf < 4; ++nf){
      int n = n0 + wn*64 + nf*16 + r;
      #pragma unroll
      for (int j = 0; j < 4; ++j){
        int m = m0 + wm*64 + mf*16 + g*4 + j;
        float val = (acc[mf][nf][j] + bv[nf]) * scale;
        if (MODE == 2){
          ((float*)Cout_v)[(size_t)m*C_ + n] = val;
        } else {
          int nn = n & 1023;
          int b = m >> 11, t = m & (T_-1), hgl = nn >> 6, d = nn & 63;
          size_t addr;
          if (which <= 1) addr = (size_t)which*M_*C_ + ((((size_t)b*H_ + hgl)*T_ + t) << 6) + d;
          else            addr = (size_t)2*M_*C_ + (((size_t)b*H_ + hgl)*D_ + d)*T_ + t;
          ((unsigned short*)Cout_v)[addr] = f2bf(val);
        }
      }
    }
  }
}

// ---------------- Flash attention v4: 8-wave blocks, LDS-staged KV, counted vmcnt ----
// Q[B,H,T,D] (pre-scaled), K[B,H,T,D], Vt[B,H,D,T] -> ctx[B,T,C] bf16
// grid: 512 blocks x 512 thr; wgid = pair*64 + bh (XCD = bh%8)
__global__ __launch_bounds__(512, 4)
void attn_k(const unsigned short* __restrict__ Q,
            const unsigned short* __restrict__ K,
            const unsigned short* __restrict__ Vt,
            unsigned short* __restrict__ ctx)
{
  __shared__ alignas(16) unsigned short Kbuf[2][64*64];
  __shared__ alignas(16) unsigned short Vbuf[2][64*64];
  __shared__ alignas(16) unsigned short obuf[8][32*64];
  const int tid  = threadIdx.x;
  const int lane = tid & 63, w = tid >> 6;   // 8 warps
  const int h    = lane >> 5;
  const int ql   = lane & 31;
  const int wgid = blockIdx.x;
  const int pr   = wgid >> 6;                // 0..7
  const int bh   = wgid & 63;
  const size_t base = (size_t)bh * T_ * D_;
  const int bb = bh >> 4, hh = bh & 15;

  // stage one 64x64 K tile + 64x64 Vt tile (XOR-swizzled via global source)
  auto stageKV = [&](int buf, int kv0){
    int c  = tid;            // 0..511 chunk of 16B
    int rr = c >> 3, cs = c & 7, cc = cs ^ (rr & 7);
    gload_lds16(&K [base + (size_t)(kv0 + rr)*D_ + cc*8], &Kbuf[buf][c*8]);
    gload_lds16(&Vt[base + (size_t)rr*T_ + kv0 + cc*8],   &Vbuf[buf][c*8]);
  };

  #pragma unroll 1
  for (int hf = 0; hf < 2; ++hf){
    const int reg    = hf ? (7 - pr) : pr;   // 256-row q-region
    const int qlo    = reg*256 + w*32;
    const int own_nt = (qlo >> 6) + 1;       // tiles this warp needs
    const int NT     = reg*4 + 4;            // tiles staged (even)

    bf16x8 qf[4];
    #pragma unroll
    for (int kc = 0; kc < 4; ++kc)
      qf[kc] = *(const bf16x8*)&Q[base + (size_t)(qlo + ql)*D_ + kc*16 + h*8];

    f32x16 oacc[2] = {};
    float m_run = -1e30f, l_run = 0.f;

    stageKV(0, 0);
    for (int kv = 0; kv < NT; ++kv){
      const int cur = kv & 1;
      if (kv + 1 < NT){
        stageKV(cur^1, (kv+1)*64);
        asm volatile("s_waitcnt vmcnt(2)" ::: "memory");   // tile kv landed; kv+1 in flight
      } else {
        asm volatile("s_waitcnt vmcnt(0)" ::: "memory");
      }
      __builtin_amdgcn_s_barrier();          // buf[cur] ready for all warps

      if (kv < own_nt){
        const bool partial = (kv == own_nt - 1);
        // ---- QK^T (swapped) from LDS ----
        f32x16 st[2];
        #pragma unroll
        for (int t = 0; t < 2; ++t){
          f32x16 s = {};
          const int R = t*32 + ql;
          #pragma unroll
          for (int kc = 0; kc < 4; ++kc){
            int off = R*128 + ((((kc<<1)|h) ^ (R & 7)) << 4);
            bf16x8 kfr = *(const bf16x8*)((const char*)&Kbuf[cur][0] + off);
            s = mfma32(kfr, qf[kc], s);
          }
          st[t] = s;
        }
        // ---- mask (diagonal tile only) ----
        if (partial){
          #pragma unroll
          for (int t = 0; t < 2; ++t)
            #pragma unroll
            for (int rg = 0; rg < 16; ++rg){
              int kvi = kv*64 + t*32 + (rg&3) + 8*(rg>>2) + 4*h;
              if (kvi > qlo + ql) st[t][rg] = -1e30f;
            }
        }
        // ---- tree max ----
        float a0 = st[0][0], a1 = st[0][1], a2 = st[0][2], a3 = st[0][3];
        #pragma unroll
        for (int i = 4; i < 16; i += 4){
          a0 = fmaxf(a0, st[0][i]);   a1 = fmaxf(a1, st[0][i+1]);
          a2 = fmaxf(a2, st[0][i+2]); a3 = fmaxf(a3, st[0][i+3]);
        }
        #pragma unroll
        for (int i = 0; i < 16; i += 4){
          a0 = fmaxf(a0, st[1][i]);   a1 = fmaxf(a1, st[1][i+1]);
          a2 = fmaxf(a2, st[1][i+2]); a3 = fmaxf(a3, st[1][i+3]);
        }
        float mx = fmaxf(fmaxf(a0, a1), fmaxf(a2, a3));
        mx = fmaxf(mx, __shfl_xor(mx, 32, 64));
        float mnew  = fmaxf(m_run, mx);
        float alpha = ex2(m_run - mnew);
        // ---- exp (in place) + tree sum ----
        float s0 = 0.f, s1 = 0.f, s2 = 0.f, s3 = 0.f;
        #pragma unroll
        for (int t = 0; t < 2; ++t)
          #pragma unroll
          for (int i = 0; i < 16; i += 4){
            st[t][i]   = ex2(st[t][i]   - mnew); s0 += st[t][i];
            st[t][i+1] = ex2(st[t][i+1] - mnew); s1 += st[t][i+1];
            st[t][i+2] = ex2(st[t][i+2] - mnew); s2 += st[t][i+2];
            st[t][i+3] = ex2(st[t][i+3] - mnew); s3 += st[t][i+3];
          }
        float rs = (s0 + s1) + (s2 + s3);
        rs += __shfl_xor(rs, 32, 64);
        l_run = l_run * alpha + rs;
        m_run = mnew;
        oacc[0] = oacc[0] * alpha;
        oacc[1] = oacc[1] * alpha;
        // ---- P -> bf16 frags (cvt_pk + permlane32_swap) ----
        bf16x8 pf[4];
        #pragma unroll
        for (int t = 0; t < 2; ++t)
          #pragma unroll
          for (int cl = 0; cl < 2; ++cl){
            int b0 = cl*8;
            unsigned pkA = cvtpk(st[t][b0+0], st[t][b0+1]);
            unsigned pkB = cvtpk(st[t][b0+4], st[t][b0+5]);
            unsigned pkC = cvtpk(st[t][b0+2], st[t][b0+3]);
            unsigned pkD = cvtpk(st[t][b0+6], st[t][b0+7]);
            i32x2v r02 = __builtin_amdgcn_permlane32_swap((int)pkA, (int)pkB, false, false);
            i32x2v r13 = __builtin_amdgcn_permlane32_swap((int)pkC, (int)pkD, false, false);
            union { int d[4]; bf16x8 v; } u;
            u.d[0] = r02[0]; u.d[1] = r13[0]; u.d[2] = r02[1]; u.d[3] = r13[1];
            pf[t*2+cl] = u.v;
          }
        // ---- PV from LDS V ----
        #pragma unroll
        for (int dt = 0; dt < 2; ++dt){
          const int R = dt*32 + ql;
          #pragma unroll
          for (int c = 0; c < 4; ++c){
            int off = R*128 + ((((c<<1)|h) ^ (R & 7)) << 4);
            bf16x8 vfr = *(const bf16x8*)((const char*)&Vbuf[cur][0] + off);
            oacc[dt] = mfma32(vfr, pf[c], oacc[dt]);
          }
        }
      }
      __builtin_amdgcn_s_barrier();          // all reads done before next overwrite
    }

    // ---- epilogue: O^T -> LDS (swizzled) -> coalesced global ----
    float inv = __builtin_amdgcn_rcpf(l_run);
    unsigned short* ob = &obuf[w][0];
    #pragma unroll
    for (int dt = 0; dt < 2; ++dt)
      #pragma unroll
      for (int rg = 0; rg < 16; rg += 2){
        int d = dt*32 + (rg&3) + 8*(rg>>2) + 4*h;
        unsigned pk = cvtpk(oacc[dt][rg]*inv, oacc[dt][rg+1]*inv);
        int off = (ql*128 + d*2) ^ ((ql&7)<<4);
        *(unsigned*)((char*)ob + off) = pk;
      }
    __builtin_amdgcn_s_waitcnt(0);  // lgkmcnt(0): same-wave LDS visibility
    const size_t orow = ((size_t)bb*T_ + qlo + ql)*C_ + hh*64 + h*32;
    #pragma unroll
    for (int x = 0; x < 4; ++x){
      int off = (ql*128 + h*64 + x*16) ^ ((ql&7)<<4);
      bf16x8 v = *(const bf16x8*)((const char*)ob + off);
      *(bf16x8*)&ctx[orow + x*8] = v;
    }
    __syncthreads();   // full drain between region phases
  }
}

extern "C" void kernel_launch(void* const* d_in, const int* in_sizes, int n_in,
                              void* d_out, int out_size, void* d_ws, size_t ws_size,
                              hipStream_t stream)
{
  const float* x  = (const float*)d_in[0];
  const float* Wq = (const float*)d_in[1];
  const float* bq = (const float*)d_in[2];
  const float* Wk = (const float*)d_in[3];
  const float* bk = (const float*)d_in[4];
  const float* Wv = (const float*)d_in[5];
  const float* bv = (const float*)d_in[6];
  const float* Wo = (const float*)d_in[7];
  const float* bo = (const float*)d_in[8];
  float* out = (float*)d_out;

  const size_t NELT = (size_t)M_ * C_;   // 8.39M
  const size_t WELT = (size_t)C_ * C_;   // 1.05M
  unsigned short* xb  = (unsigned short*)d_ws;
  unsigned short* Wcb = xb  + NELT;          // Wq|Wk|Wv|Wo concat (bf16)
  unsigned short* Wob = Wcb + 3*WELT;
  unsigned short* Qb  = Wob + WELT;          // Q | K | Vt contiguous
  unsigned short* Kb  = Qb  + NELT;
  unsigned short* Vtb = Kb  + NELT;
  unsigned short* ctx = Vtb + NELT;

  convert_all_k<<<dim3((unsigned)((NELT + 4*WELT)/8/256)), 256, 0, stream>>>(x, Wq, Wk, Wv, Wo, xb);

  gemm_bias_k<0><<<dim3(3*C_/128, M_/128), 256, 0, stream>>>(xb, Wcb, bq, bk, bv, Qb);
  attn_k<<<dim3(512), 512, 0, stream>>>(Qb, Kb, Vtb, ctx);
  gemm_bias_k<2><<<dim3(C_/128, M_/128), 256, 0, stream>>>(ctx, Wob, bo, bo, bo, out);
}